// Round 1
// baseline (218.126 us; speedup 1.0000x reference)
//
#include <hip/hip_runtime.h>

// SPGG Q-learning step on a 2048x2048 torus.
// Outputs (concatenated float32 in d_out): Q_new [N*4], type_t1 [N] (as float),
// profit [N].  Workspace holds pm (the fermi profit matrix = upd) [N floats].
//
// Numerics: every f32 op that feeds the fermi decision (lp <= W) is done with
// __f*_rn intrinsics in the reference's exact evaluation order so no FMA
// contraction / reassociation can perturb the branch. exp is computed in
// double and rounded once -> correctly-rounded f32 exp.

#define LSIDE 2048
#define LMASK 2047
#define LSHIFT 11
#define NCELL (LSIDE * LSIDE)

__global__ __launch_bounds__(256) void spgg_k1(
    const int* __restrict__ tmin,   // type_t_minus
    const int* __restrict__ tt,     // type_t
    const float* __restrict__ Q,    // Q_tensor [N,4]
    float* __restrict__ Qn,         // out: Q_new [N,4]
    float* __restrict__ prof,       // out: profit [N]
    float* __restrict__ pm)         // ws:  fermi profit matrix [N]
{
    int idx = blockIdx.x * blockDim.x + threadIdx.x;
    int i = idx >> LSHIFT;
    int j = idx & LMASK;
    int im1 = (i - 1) & LMASK, ip1 = (i + 1) & LMASK;
    int jm1 = (j - 1) & LMASK, jp1 = (j + 1) & LMASK;
    int im2 = (i - 2) & LMASK, ip2 = (i + 2) & LMASK;
    int jm2 = (j - 2) & LMASK, jp2 = (j + 2) & LMASK;

    // 13-point (radius-2 plus-of-plus) footprint of the cooperator mask.
#define TT(r, c) (tt[((r) << LSHIFT) | (c)] == 1)
    int v_cc = tt[(i << LSHIFT) | j];
    int c_cc = (v_cc == 1);
    int c_um = TT(im1, j);
    int c_dm = TT(ip1, j);
    int c_ml = TT(i, jm1);
    int c_mr = TT(i, jp1);
    int c_uu = TT(im2, j);
    int c_dd = TT(ip2, j);
    int c_ll = TT(i, jm2);
    int c_rr = TT(i, jp2);
    int c_ul = TT(im1, jm1);
    int c_ur = TT(im1, jp1);
    int c_dl = TT(ip1, jm1);
    int c_dr = TT(ip1, jp1);
#undef TT

    // coop_num at center and its 4 plus-neighbors (exact small ints).
    int cn_c = c_cc + c_um + c_dm + c_ml + c_mr;
    int cn_u = c_um + c_uu + c_cc + c_ul + c_ur;   // at (i-1, j)
    int cn_d = c_dm + c_cc + c_dd + c_dl + c_dr;   // at (i+1, j)
    int cn_l = c_ml + c_ul + c_dl + c_ll + c_cc;   // at (i, j-1)
    int cn_r = c_mr + c_ur + c_dr + c_cc + c_rr;   // at (i, j+1)

    const float KB = 0.5554f;   // float32(R / 5.0)
    float b_c = __fmul_rn((float)cn_c, KB);
    float b_u = __fmul_rn((float)cn_u, KB);
    float b_d = __fmul_rn((float)cn_d, KB);
    float b_l = __fmul_rn((float)cn_l, KB);
    float b_r = __fmul_rn((float)cn_r, KB);

    // plus_sum order in the reference: self + up + down + left + right.
    float s0 = __fadd_rn(__fadd_rn(__fadd_rn(__fadd_rn(b_c, b_u), b_d), b_l), b_r);
    float s1 = __fadd_rn(__fadd_rn(__fadd_rn(__fadd_rn(
                   __fsub_rn(b_c, 1.0f), __fsub_rn(b_u, 1.0f)),
                   __fsub_rn(b_d, 1.0f)), __fsub_rn(b_l, 1.0f)),
                   __fsub_rn(b_r, 1.0f));
    float profit = c_cc ? s1 : s0;

    // Q-learning update (one float4 row per cell).
    float4 qr = ((const float4*)Q)[idx];
    int B = v_cc;           // current action (values are 0/1)
    int A = tmin[idx];      // previous action
    float q0 = (B == 0) ? qr.x : qr.z;   // Q[n, B, 0]
    float q1 = (B == 0) ? qr.y : qr.w;   // Q[n, B, 1]
    float mx = fmaxf(q0, q1);
    int k = A * 2 + B;
    float old = (k == 0) ? qr.x : ((k == 1) ? qr.y : ((k == 2) ? qr.z : qr.w));

    const float ETA       = 0.8f;
    const float ONE_M_ETA = 0.2f;   // float32(1.0 - 0.8) as numpy promotes it
    const float GAMMA     = 0.8f;
    float t0 = __fmul_rn(GAMMA, mx);          // gamma * max_b Q[n,B,b]
    float t1 = __fadd_rn(profit, t0);
    float t2 = __fmul_rn(ETA, t1);
    float t3 = __fmul_rn(ONE_M_ETA, old);
    float upd = __fadd_rn(t3, t2);

    float4 qo;
    qo.x = (k == 0) ? upd : qr.x;
    qo.y = (k == 1) ? upd : qr.y;
    qo.z = (k == 2) ? upd : qr.z;
    qo.w = (k == 3) ? upd : qr.w;
    ((float4*)Qn)[idx] = qo;
    prof[idx] = profit;
    pm[idx]   = upd;
}

__global__ __launch_bounds__(256) void spgg_k2(
    const int* __restrict__ tt,
    const int* __restrict__ ldir,
    const float* __restrict__ lp,
    const float* __restrict__ pm,
    float* __restrict__ t1out)
{
    int idx = blockIdx.x * blockDim.x + threadIdx.x;
    int i = idx >> LSHIFT;
    int j = idx & LMASK;
    int dir = ldir[idx];
    // dir: 0=left(j-1) 1=right(j+1) 2=up(i-1) 3=down(i+1)  (branchless)
    int ni = (i + ((dir == 3) - (dir == 2))) & LMASK;
    int nj = (j + ((dir == 1) - (dir == 0))) & LMASK;
    int nidx = (ni << LSHIFT) | nj;

    float pmc = pm[idx];
    float pmn = pm[nidx];
    float e1 = __fsub_rn(pmc, pmn);
    float e2 = __fmul_rn(e1, 2.0f);          // / K_FERMI(0.5): exact scaling
    float ex = (float)exp((double)e2);       // correctly-rounded f32 exp
    float den = __fadd_rn(1.0f, ex);
    float W = __fdiv_rn(1.0f, den);
    float p = lp[idx];
    int sel = (p <= W) ? tt[nidx] : tt[idx];
    t1out[idx] = (float)sel;
}

extern "C" void kernel_launch(void* const* d_in, const int* in_sizes, int n_in,
                              void* d_out, int out_size, void* d_ws, size_t ws_size,
                              hipStream_t stream) {
    const int*   type_t_minus = (const int*)d_in[0];
    const int*   type_t       = (const int*)d_in[1];
    const float* Q_tensor     = (const float*)d_in[2];
    const int*   ldir         = (const int*)d_in[3];
    const float* lprob        = (const float*)d_in[4];

    float* out    = (float*)d_out;
    float* Qn     = out;                       // [N*4]
    float* t1out  = out + (size_t)4 * NCELL;   // [N]
    float* prof   = out + (size_t)5 * NCELL;   // [N]
    float* pm     = (float*)d_ws;              // [N] floats (16 MiB)

    const int threads = 256;
    const int blocks  = NCELL / threads;       // 16384
    spgg_k1<<<blocks, threads, 0, stream>>>(type_t_minus, type_t, Q_tensor,
                                            Qn, prof, pm);
    spgg_k2<<<blocks, threads, 0, stream>>>(type_t, ldir, lprob, pm, t1out);
}